// Round 5
// baseline (527.481 us; speedup 1.0000x reference)
//
#include <hip/hip_runtime.h>
#include <hip/hip_bf16.h>

#define NNA 50000
#define NNB 50000
#define NE  800000
#define HD  256
#define EMBD 128

typedef __attribute__((ext_vector_type(4))) int            i32x4;
typedef __attribute__((ext_vector_type(4))) float          f32x4;
typedef __attribute__((ext_vector_type(8))) short          bf16x8;
typedef __attribute__((ext_vector_type(4))) unsigned short u16x4;
typedef __attribute__((ext_vector_type(8))) unsigned short u16x8;

static __device__ __forceinline__ float bf2f(unsigned short u) {
  union { unsigned int i; float f; } v; v.i = ((unsigned int)u) << 16; return v.f;
}
static __device__ __forceinline__ unsigned short f2bf(float f) {
  __hip_bfloat16 h = __float2bfloat16(f);
  return *reinterpret_cast<unsigned short*>(&h);
}

static __device__ __forceinline__ void gload_lds16(const void* g, void* l) {
  __builtin_amdgcn_global_load_lds((const __attribute__((address_space(1))) void*)g,
                                   (__attribute__((address_space(3))) void*)l, 16, 0, 0);
}

// ---------------- merged prep kernel ----------------
// seg0: WcatT[l][t][n][k] bf16 [2][2][256][512]  (524288 ids)
// seg1: bias [l][t][n] f32 (1024 ids)
// seg2: linWT [n][k] bf16 128x256 (32768 ids)
__global__ void k_prep(const float* __restrict__ Wl, const float* __restrict__ Wr,
                       const float* __restrict__ bl, const float* __restrict__ linW,
                       unsigned short* __restrict__ WcatT, float* __restrict__ bias,
                       unsigned short* __restrict__ linWT) {
  int id = blockIdx.x * 256 + threadIdx.x;
  if (id < 2 * 2 * 512 * 256) {
    int n = id & 255;
    int k = (id >> 8) & 511;
    int t = (id >> 17) & 1;
    int l = id >> 18;
    int rn = (t == 0) ? 1 : 0;
    int rs = (t == 0) ? 2 : 3;
    float v;
    if (k < HD) {
      v = Wl[((l * 4 + rn) * HD + k) * HD + n];
    } else {
      int kk = k - HD;
      v = Wr[((l * 4 + rn) * HD + kk) * HD + n]
        + Wl[((l * 4 + rs) * HD + kk) * HD + n]
        + Wr[((l * 4 + rs) * HD + kk) * HD + n];
    }
    WcatT[((l * 2 + t) * HD + n) * 512 + k] = f2bf(v);
    return;
  }
  int id1 = id - 2 * 2 * 512 * 256;
  if (id1 < 2 * 2 * 256) {
    int n = id1 & 255; int t = (id1 >> 8) & 1; int l = id1 >> 9;
    int rn = (t == 0) ? 1 : 0;
    int rs = (t == 0) ? 2 : 3;
    bias[id1] = bl[(l * 4 + rn) * HD + n] + bl[(l * 4 + rs) * HD + n];
    return;
  }
  int id2 = id1 - 2 * 2 * 256;
  if (id2 < EMBD * HD) {
    int k = id2 & 255; int n = id2 >> 8;
    linWT[n * HD + k] = f2bf(linW[k * EMBD + n]);
  }
}

// ---------------- merged f32->bf16 conversion (a then b) ----------------
__global__ void k_convert(const float* __restrict__ xa, const float* __restrict__ xb,
                          unsigned short* __restrict__ out) {
  const int n4a = NNA * HD / 4;
  const int n4  = (NNA + NNB) * HD / 4;
  int i = blockIdx.x * blockDim.x + threadIdx.x;
  int stride = gridDim.x * blockDim.x;
  for (; i < n4; i += stride) {
    const float* src = (i < n4a) ? (xa + (size_t)i * 4) : (xb + (size_t)(i - n4a) * 4);
    f32x4 v = *reinterpret_cast<const f32x4*>(src);
    u16x4 o;
    o[0] = f2bf(v[0]); o[1] = f2bf(v[1]); o[2] = f2bf(v[2]); o[3] = f2bf(v[3]);
    reinterpret_cast<u16x4*>(out)[i] = o;
  }
}

// ---------------- merged adjacency bucketing ----------------
__global__ void k_fill(const int* __restrict__ e_ba, const int* __restrict__ e_ab,
                       int* __restrict__ cnt_a, int* __restrict__ slots_a,
                       int* __restrict__ cnt_b, int* __restrict__ slots_b) {
  int e = blockIdx.x * 256 + threadIdx.x;
  if (e < NE) {
    int src = e_ba[e];
    int dst = e_ba[NE + e];
    int pos = atomicAdd(&cnt_a[dst], 1);
    if (pos < 64) slots_a[dst * 64 + pos] = src;
  } else if (e < 2 * NE) {
    int f = e - NE;
    int src = e_ab[f];
    int dst = e_ab[NE + f];
    int pos = atomicAdd(&cnt_b[dst], 1);
    if (pos < 64) slots_b[dst * 64 + pos] = src;
  }
}

// ---------------- atomic-free mean aggregation (both types fused) ----------------
__global__ __launch_bounds__(256)
void k_aggregate(const unsigned short* __restrict__ xa,
                 const unsigned short* __restrict__ xb,
                 const int* __restrict__ slots_a, const int* __restrict__ cnt_a,
                 const int* __restrict__ slots_b, const int* __restrict__ cnt_b,
                 unsigned short* __restrict__ mean_a, unsigned short* __restrict__ mean_b) {
  int w = blockIdx.x * 4 + (threadIdx.x >> 6);
  int lane = threadIdx.x & 63;
  const unsigned short* xsrc;
  const int* sl;
  int deg;
  unsigned short* outp;
  if (w < NNA) {
    xsrc = xb; sl = slots_a + (size_t)w * 64; deg = cnt_a[w];
    outp = mean_a + (size_t)w * HD;
  } else {
    int v = w - NNA;
    xsrc = xa; sl = slots_b + (size_t)v * 64; deg = cnt_b[v];
    outp = mean_b + (size_t)v * HD;
  }
  int m = deg < 64 ? deg : 64;
  int s_all = sl[lane];              // one coalesced 256B slot read per wave
  const int half = lane >> 5;
  const int l31 = lane & 31;

  float acc[8];
#pragma unroll
  for (int k = 0; k < 8; ++k) acc[k] = 0.f;

  int j = 0;
  for (; j + 8 <= m; j += 8) {
    int sj[4];
#pragma unroll
    for (int i = 0; i < 4; ++i) sj[i] = __shfl(s_all, j + 2 * i + half);
    u16x8 v[4];
#pragma unroll
    for (int i = 0; i < 4; ++i)
      v[i] = *reinterpret_cast<const u16x8*>(xsrc + (size_t)sj[i] * HD + l31 * 8);
#pragma unroll
    for (int i = 0; i < 4; ++i)
#pragma unroll
      for (int k = 0; k < 8; ++k) acc[k] += bf2f(v[i][k]);
  }
  for (; j + 2 <= m; j += 2) {
    int sj = __shfl(s_all, j + half);
    u16x8 v = *reinterpret_cast<const u16x8*>(xsrc + (size_t)sj * HD + l31 * 8);
#pragma unroll
    for (int k = 0; k < 8; ++k) acc[k] += bf2f(v[k]);
  }
  if (j < m && half == 0) {
    int sj = __shfl(s_all, j);
    u16x8 v = *reinterpret_cast<const u16x8*>(xsrc + (size_t)sj * HD + l31 * 8);
#pragma unroll
    for (int k = 0; k < 8; ++k) acc[k] += bf2f(v[k]);
  }

#pragma unroll
  for (int k = 0; k < 8; ++k) acc[k] += __shfl_xor(acc[k], 32);

  float inv = deg > 0 ? 1.0f / (float)deg : 0.0f;
  if (half == 0) {
    u16x8 o;
#pragma unroll
    for (int k = 0; k < 8; ++k) o[k] = f2bf(acc[k] * inv);
    *reinterpret_cast<u16x8*>(outp + l31 * 8) = o;
  }
}

// ---------------- fused bf16 MFMA GEMM, global_load_lds + double buffer ----------------
// C[M][N] = relu?( [Alo | Ahi](M x Ktot) @ BT^T + bias )
// Alo/Ahi: bf16 row-major [M][256]. BT: bf16 row-major [N][Ktot].
// BM=BN=128, BK=64, 256 threads = 4 waves (2x2), 64x64 per wave.
// LDS: Abuf[2][16K] @0, Bbuf[2][16K] @32K (64KB total -> 2 blocks/CU).
// Staging: linear LDS dest (wave-uniform base + lane*16), pre-swizzled global
// source ((l&7)^(l>>3))<<4, swizzled ds_read  (both-sides rule).
template <bool RELU, bool OUTF32>
__global__ __launch_bounds__(256)
void k_gemm(const unsigned short* __restrict__ Alo,
            const unsigned short* __restrict__ Ahi,
            const unsigned short* __restrict__ BT,
            const float* __restrict__ bias,
            void* __restrict__ Cout,
            int M, int N, int Ktot, int Klo,
            long long sA, long long sB, long long sBias, long long sCbytes) {
  const int z = blockIdx.z;
  Alo += (long long)z * sA;
  Ahi += (long long)z * sA;
  BT += (long long)z * sB;
  bias += (long long)z * sBias;
  Cout = (void*)((char*)Cout + (long long)z * sCbytes);

  __shared__ char smem[65536];
  const int t = threadIdx.x;
  const int bm = blockIdx.x, bn = blockIdx.y;
  const int lane = t & 63, wid = t >> 6;
  const int wm = wid >> 1, wn = wid & 1;
  const int l15 = lane & 15, l4 = lane >> 4;
  const int rgrp = lane >> 3;                       // row within 8-row group
  const int boff = (((lane & 7) ^ rgrp) << 4);      // pre-swizzled byte off in 128B chunk

  f32x4 acc[4][4];
#pragma unroll
  for (int i = 0; i < 4; ++i)
#pragma unroll
    for (int j = 0; j < 4; ++j) acc[i][j] = (f32x4){0.f, 0.f, 0.f, 0.f};

  const int nks = Ktot >> 6;

  auto stage = [&](int ks, int buf) {
    const int kglob = ks << 6;
    const unsigned short* Asrc = (kglob < Klo) ? Alo : Ahi;
    const int kbase = (kglob < Klo) ? kglob : (kglob - Klo);
    char* sA_ = smem + buf * 16384;
    char* sB_ = smem + 32768 + buf * 16384;
#pragma unroll
    for (int i = 0; i < 4; ++i) {
      int rloc = wid * 32 + i * 8;                  // uniform per wave
      int rA = bm * 128 + rloc + rgrp;
      if (rA >= M) rA = M - 1;
      const char* ga = (const char*)(Asrc + (size_t)rA * HD + kbase) + boff;
      gload_lds16(ga, sA_ + rloc * 128);
      int rB = bn * 128 + rloc + rgrp;
      const char* gb = (const char*)(BT + (size_t)rB * Ktot + kglob) + boff;
      gload_lds16(gb, sB_ + rloc * 128);
    }
  };

  stage(0, 0);
  __syncthreads();   // full drain (vmcnt+lgkm) + barrier

  for (int ks = 0; ks < nks; ++ks) {
    if (ks + 1 < nks) stage(ks + 1, (ks + 1) & 1);
    const char* sA_ = smem + (ks & 1) * 16384;
    const char* sB_ = smem + 32768 + (ks & 1) * 16384;
#pragma unroll
    for (int kk = 0; kk < 2; ++kk) {
      bf16x8 af[4], bfr[4];
#pragma unroll
      for (int f = 0; f < 4; ++f) {
        int r = wm * 64 + f * 16 + l15;
        af[f] = *reinterpret_cast<const bf16x8*>(
            sA_ + r * 128 + ((kk * 64 + l4 * 16) ^ ((r & 7) << 4)));
        int n = wn * 64 + f * 16 + l15;
        bfr[f] = *reinterpret_cast<const bf16x8*>(
            sB_ + n * 128 + ((kk * 64 + l4 * 16) ^ ((n & 7) << 4)));
      }
#pragma unroll
      for (int fm = 0; fm < 4; ++fm)
#pragma unroll
        for (int fn = 0; fn < 4; ++fn)
          acc[fm][fn] = __builtin_amdgcn_mfma_f32_16x16x32_bf16(af[fm], bfr[fn], acc[fm][fn], 0, 0, 0);
    }
    __syncthreads();  // drains the stage's vmcnt + protects buffer reuse
  }

#pragma unroll
  for (int fm = 0; fm < 4; ++fm) {
    int row0 = bm * 128 + wm * 64 + fm * 16 + l4 * 4;
#pragma unroll
    for (int fn = 0; fn < 4; ++fn) {
      int col = bn * 128 + wn * 64 + fn * 16 + l15;
      float bv = bias[col];
      f32x4 d = acc[fm][fn];
#pragma unroll
      for (int r = 0; r < 4; ++r) {
        int rg = row0 + r;
        if (rg < M) {
          float v = d[r] + bv;
          if (RELU) v = v > 0.f ? v : 0.f;
          if (OUTF32)
            reinterpret_cast<float*>(Cout)[(size_t)rg * N + col] = v;
          else
            reinterpret_cast<unsigned short*>(Cout)[(size_t)rg * N + col] = f2bf(v);
        }
      }
    }
  }
}

// ---------------- launch ----------------

extern "C" void kernel_launch(void* const* d_in, const int* in_sizes, int n_in,
                              void* d_out, int out_size, void* d_ws, size_t ws_size,
                              hipStream_t stream) {
  const float* x_a  = (const float*)d_in[0];
  const float* x_b  = (const float*)d_in[1];
  const int*   e_ab = (const int*)d_in[2];
  const int*   e_ba = (const int*)d_in[3];
  const float* Wl   = (const float*)d_in[4];
  const float* bl   = (const float*)d_in[5];
  const float* Wr   = (const float*)d_in[6];
  const float* linW = (const float*)d_in[7];
  const float* linb = (const float*)d_in[8];
  float* out = (float*)d_out;

  char* ws = (char*)d_ws;
  size_t off = 0;
  auto alloc = [&](size_t bytes) {
    char* p = ws + off;
    off += (bytes + 255) & ~(size_t)255;
    return p;
  };
  unsigned short* x0   = (unsigned short*)alloc((size_t)2 * NNA * HD * 2);
  unsigned short* x1   = (unsigned short*)alloc((size_t)2 * NNA * HD * 2);
  unsigned short* mean = (unsigned short*)alloc((size_t)2 * NNA * HD * 2);
  int* slots_a = (int*)alloc((size_t)NNA * 64 * 4);
  int* slots_b = (int*)alloc((size_t)NNB * 64 * 4);
  int* cnt_a   = (int*)alloc((size_t)NNA * 4);
  int* cnt_b   = (int*)alloc((size_t)NNB * 4);
  unsigned short* wcatT  = (unsigned short*)alloc((size_t)2 * 2 * 256 * 512 * 2);
  float*          biasv  = (float*)alloc((size_t)2 * 2 * 256 * 4);
  unsigned short* linWT  = (unsigned short*)alloc((size_t)EMBD * HD * 2);
  (void)ws_size; (void)in_sizes; (void)n_in; (void)out_size;

  hipMemsetAsync(cnt_a, 0, (size_t)NNA * 4, stream);
  hipMemsetAsync(cnt_b, 0, (size_t)NNB * 4, stream);

  k_prep<<<(2 * 2 * 512 * 256 + 1024 + 32768 + 255) / 256, 256, 0, stream>>>(
      Wl, Wr, bl, linW, wcatT, biasv, linWT);
  k_convert<<<2048, 256, 0, stream>>>(x_a, x_b, x0);
  k_fill<<<(2 * NE + 255) / 256, 256, 0, stream>>>(e_ba, e_ab, cnt_a, slots_a, cnt_b, slots_b);

  unsigned short* xcur = x0;
  unsigned short* xnxt = x1;

  for (int l = 0; l < 2; ++l) {
    k_aggregate<<<(NNA + NNB) / 4, 256, 0, stream>>>(
        xcur, xcur + (size_t)NNA * HD, slots_a, cnt_a, slots_b, cnt_b,
        mean, mean + (size_t)NNA * HD);
    dim3 g((NNA + 127) / 128, 2, 2);
    k_gemm<true, false><<<g, 256, 0, stream>>>(
        mean, xcur, wcatT + (size_t)l * 2 * 256 * 512, biasv + l * 2 * 256, xnxt,
        NNA, 256, 512, 256,
        (long long)NNA * HD, 256 * 512, 256, (long long)NNA * HD * 2);
    unsigned short* tmp = xcur; xcur = xnxt; xnxt = tmp;
  }

  dim3 gf((NNA + 127) / 128, 1, 2);
  k_gemm<false, true><<<gf, 256, 0, stream>>>(
      xcur, xcur, linWT, linb, out,
      NNA, EMBD, 256, 256,
      (long long)NNA * HD, 0, 0, (long long)NNA * EMBD * 4);
}